// Round 2
// baseline (290.723 us; speedup 1.0000x reference)
//
#include <hip/hip_runtime.h>

// Correlation layer, MAX_DISP=4: out[b, dx*9+dy, h, w] =
//   mean_c x1[b,c,h,w] * x2[b,c,h+dx-4,w+dy-4]  (x2 zero-padded)
// x1,x2: (8,64,256,256) fp32.  out: (8,81,256,256) fp32.
//
// Block = 256 threads (4 waves). Wave i handles row h0+i for one dx.
// Each thread: 4 consecutive w, 9 dy accumulators. Register double-buffered
// channel loop (load c+1 while FMA'ing c) to hide L1/L2 latency.

namespace {
constexpr int kB = 8;
constexpr int kC = 64;
constexpr int kH = 256;
constexpr int kW = 256;
constexpr int kD = 9;          // 2*4+1
constexpr int kMD = 4;
constexpr int kChanStride = kH * kW;
}  // namespace

__global__ __launch_bounds__(256) void corr_kernel(
    const float* __restrict__ x1, const float* __restrict__ x2,
    float* __restrict__ out) {
  const int bx = blockIdx.x;
  const int dx = bx % kD;
  const int hg = (bx / kD) % (kH / 4);
  const int b  = bx / (kD * (kH / 4));
  const int wave = (int)threadIdx.x >> 6;
  const int lane = (int)threadIdx.x & 63;
  const int h   = hg * 4 + wave;
  const int row = h + dx - kMD;          // x2 source row
  const int w0  = lane * 4;

  float acc[kD][4];
#pragma unroll
  for (int dy = 0; dy < kD; ++dy)
#pragma unroll
    for (int j = 0; j < 4; ++j) acc[dy][j] = 0.0f;

  if (row >= 0 && row < kH) {
    const float* p1 = x1 + ((size_t)(b * kC) * kH + h) * kW + w0;
    const float* p2 = x2 + ((size_t)(b * kC) * kH + row) * kW + w0;
    const bool hasL = (w0 >= 4);
    const bool hasR = (w0 + 7 < kW);

    // prologue: load channel 0
    float4 a  = *reinterpret_cast<const float4*>(p1);
    float4 tB = *reinterpret_cast<const float4*>(p2);
    float4 tA = make_float4(0.f, 0.f, 0.f, 0.f);
    float4 tC = make_float4(0.f, 0.f, 0.f, 0.f);
    if (hasL) tA = *reinterpret_cast<const float4*>(p2 - 4);
    if (hasR) tC = *reinterpret_cast<const float4*>(p2 + 4);

    for (int c = 0; c < kC; ++c) {
      // issue next channel's loads before consuming current regs
      float4 na = a, nA = tA, nB = tB, nC = tC;
      if (c + 1 < kC) {
        p1 += kChanStride;
        p2 += kChanStride;
        na = *reinterpret_cast<const float4*>(p1);
        nB = *reinterpret_cast<const float4*>(p2);
        nA = make_float4(0.f, 0.f, 0.f, 0.f);
        nC = make_float4(0.f, 0.f, 0.f, 0.f);
        if (hasL) nA = *reinterpret_cast<const float4*>(p2 - 4);
        if (hasR) nC = *reinterpret_cast<const float4*>(p2 + 4);
      }

      const float av[4] = {a.x, a.y, a.z, a.w};
      const float t[12] = {tA.x, tA.y, tA.z, tA.w,
                           tB.x, tB.y, tB.z, tB.w,
                           tC.x, tC.y, tC.z, tC.w};
      // output col w0+j, shift dy: x2 col = w0 + j + dy - 4  ->  t[j + dy]
#pragma unroll
      for (int dy = 0; dy < kD; ++dy)
#pragma unroll
        for (int j = 0; j < 4; ++j)
          acc[dy][j] = fmaf(av[j], t[dy + j], acc[dy][j]);

      a = na; tA = nA; tB = nB; tC = nC;
    }
  }

  const float inv = 1.0f / (float)kC;
  float* po = out + (((size_t)b * (kD * kD) + dx * kD) * kH + h) * kW + w0;
#pragma unroll
  for (int dy = 0; dy < kD; ++dy) {
    float4 o = make_float4(acc[dy][0] * inv, acc[dy][1] * inv,
                           acc[dy][2] * inv, acc[dy][3] * inv);
    *reinterpret_cast<float4*>(po) = o;
    po += (size_t)kH * kW;
  }
}

extern "C" void kernel_launch(void* const* d_in, const int* in_sizes, int n_in,
                              void* d_out, int out_size, void* d_ws, size_t ws_size,
                              hipStream_t stream) {
  const float* x1 = (const float*)d_in[0];
  const float* x2 = (const float*)d_in[1];
  float* out = (float*)d_out;
  const int grid = kB * (kH / 4) * kD;  // 4608 blocks, 4 waves each
  corr_kernel<<<grid, 256, 0, stream>>>(x1, x2, out);
}

// Round 3
// 216.018 us; speedup vs baseline: 1.3458x; 1.3458x over previous
//
#include <hip/hip_runtime.h>

// Correlation layer, MAX_DISP=4: out[b, dx*9+dy, h, w] =
//   mean_c x1[b,c,h,w] * x2[b,c,h+dx-4,w+dy-4]  (x2 zero-padded)
// x1,x2: (8,64,256,256) fp32.  out: (8,81,256,256) fp32.
//
// 1 wave per block (empirically faster than 4-wave in R1 vs R2).
// XCD swizzle: hardware dispatches blockIdx round-robin over 8 XCDs, so
// decode xcd = blockIdx&7 as the BATCH index -> each XCD owns one batch
// image; the 9 dx blocks sharing an x1 row are consecutive slots on the
// SAME XCD, and x2 row sharers (9 h-neighbors) span <=81 slots -> per-XCD
// L2 (4 MiB) captures the 9x reuse that round-robin scattered before.

namespace {
constexpr int kB = 8;
constexpr int kC = 64;
constexpr int kH = 256;
constexpr int kW = 256;
constexpr int kD = 9;          // 2*4+1
constexpr int kMD = 4;
constexpr int kChanStride = kH * kW;
}  // namespace

__global__ __launch_bounds__(64) void corr_kernel(
    const float* __restrict__ x1, const float* __restrict__ x2,
    float* __restrict__ out) {
  // XCD-locality decode (grid = 8 * 256 * 9, multiple of 8)
  const int xcd  = blockIdx.x & 7;   // -> XCD id under round-robin dispatch
  const int slot = blockIdx.x >> 3;  // 0..2303, sequential on one XCD
  const int b  = xcd;
  const int h  = slot / kD;
  const int dx = slot - h * kD;

  const int row = h + dx - kMD;          // x2 source row
  const int w0  = (int)threadIdx.x * 4;  // 64 lanes * 4 = 256 = W

  float acc[kD][4];
#pragma unroll
  for (int dy = 0; dy < kD; ++dy)
#pragma unroll
    for (int j = 0; j < 4; ++j) acc[dy][j] = 0.0f;

  if (row >= 0 && row < kH) {
    const float* p1 = x1 + ((size_t)(b * kC) * kH + h) * kW + w0;
    const float* p2 = x2 + ((size_t)(b * kC) * kH + row) * kW + w0;
    const bool hasL = (w0 >= 4);
    const bool hasR = (w0 + 7 < kW);

    // prologue: load channel 0
    float4 a  = *reinterpret_cast<const float4*>(p1);
    float4 tB = *reinterpret_cast<const float4*>(p2);
    float4 tA = make_float4(0.f, 0.f, 0.f, 0.f);
    float4 tC = make_float4(0.f, 0.f, 0.f, 0.f);
    if (hasL) tA = *reinterpret_cast<const float4*>(p2 - 4);
    if (hasR) tC = *reinterpret_cast<const float4*>(p2 + 4);

    for (int c = 0; c < kC; ++c) {
      // issue next channel's loads before consuming current regs
      float4 na = a, nA = tA, nB = tB, nC = tC;
      if (c + 1 < kC) {
        p1 += kChanStride;
        p2 += kChanStride;
        na = *reinterpret_cast<const float4*>(p1);
        nB = *reinterpret_cast<const float4*>(p2);
        nA = make_float4(0.f, 0.f, 0.f, 0.f);
        nC = make_float4(0.f, 0.f, 0.f, 0.f);
        if (hasL) nA = *reinterpret_cast<const float4*>(p2 - 4);
        if (hasR) nC = *reinterpret_cast<const float4*>(p2 + 4);
      }

      const float av[4] = {a.x, a.y, a.z, a.w};
      const float t[12] = {tA.x, tA.y, tA.z, tA.w,
                           tB.x, tB.y, tB.z, tB.w,
                           tC.x, tC.y, tC.z, tC.w};
      // output col w0+j, shift dy: x2 col = w0 + j + dy - 4  ->  t[j + dy]
#pragma unroll
      for (int dy = 0; dy < kD; ++dy)
#pragma unroll
        for (int j = 0; j < 4; ++j)
          acc[dy][j] = fmaf(av[j], t[dy + j], acc[dy][j]);

      a = na; tA = nA; tB = nB; tC = nC;
    }
  }

  const float inv = 1.0f / (float)kC;
  float* po = out + (((size_t)b * (kD * kD) + dx * kD) * kH + h) * kW + w0;
#pragma unroll
  for (int dy = 0; dy < kD; ++dy) {
    float4 o = make_float4(acc[dy][0] * inv, acc[dy][1] * inv,
                           acc[dy][2] * inv, acc[dy][3] * inv);
    *reinterpret_cast<float4*>(po) = o;
    po += (size_t)kH * kW;
  }
}

extern "C" void kernel_launch(void* const* d_in, const int* in_sizes, int n_in,
                              void* d_out, int out_size, void* d_ws, size_t ws_size,
                              hipStream_t stream) {
  const float* x1 = (const float*)d_in[0];
  const float* x2 = (const float*)d_in[1];
  float* out = (float*)d_out;
  const int grid = kB * kH * kD;  // 18432 blocks, 1 wave each
  corr_kernel<<<grid, 64, 0, stream>>>(x1, x2, out);
}